// Round 2
// baseline (34226.944 us; speedup 1.0000x reference)
//
#include <hip/hip_runtime.h>
#include <math.h>

#define T_FRAMES 256
#define BATCH    64
#define NH       1024
#define NG       3072   // 3*NH
#define NMELS    80
#define FCD      256

// ---------------------------------------------------------------------------
// Transpose x: [b][t][i] -> xT [t][i][b]   (so GEMM A-tiles load coalesced)
// grid: T_FRAMES blocks of 256 threads
__global__ __launch_bounds__(256) void k_transpose_x(
    const float* __restrict__ x, float* __restrict__ xT) {
  int t = blockIdx.x;
  __shared__ float tile[BATCH][NMELS + 1];
  for (int idx = threadIdx.x; idx < BATCH * NMELS; idx += 256) {
    int b = idx / NMELS, i = idx % NMELS;
    tile[b][i] = x[((size_t)b * T_FRAMES + t) * NMELS + i];
  }
  __syncthreads();
  for (int idx = threadIdx.x; idx < BATCH * NMELS; idx += 256) {
    int i = idx / BATCH, b = idx % BATCH;
    xT[((size_t)t * NMELS + i) * BATCH + b] = tile[b][i];
  }
}

// ---------------------------------------------------------------------------
// xp[ty][g][b] = sum_k A[t0+ty][k][b] * W[g][k] + bias[g],  ty = blockIdx.y
// A: [T][K][BATCH] (k-major per t), W: [NG][K] row-major.
// grid: (NG/64, Tc), block 256. Tiles: 64 g x 64 b, KT=16. 4x4 microtile.
__global__ __launch_bounds__(256) void k_gemm_xp(
    const float* __restrict__ A, const float* __restrict__ W,
    const float* __restrict__ bias, float* __restrict__ xp, int K, int t0) {
  int ty = blockIdx.y;
  int t  = t0 + ty;
  int g0 = blockIdx.x * 64;
  __shared__ float As[16][64];   // [kt][b]
  __shared__ float Bs[16][64];   // [kt][g]

  int tid = threadIdx.x;
  int b0 = (tid & 15) * 4;       // micro-tile batch base
  int gq = tid >> 4;             // 0..15, micro-tile gate base = gq*4
  int ar = tid >> 4;             // A stage: row (kt)
  int ac = (tid & 15) * 4;       // A stage: col (b)
  int bg = tid & 63;             // B stage: g within tile
  int bk = (tid >> 6) * 4;       // B stage: k chunk

  float acc[4][4] = {{0.f}};
  const float* At = A + (size_t)t * K * BATCH;

  for (int k0 = 0; k0 < K; k0 += 16) {
    *(float4*)&As[ar][ac] = *(const float4*)&At[(size_t)(k0 + ar) * BATCH + ac];
    float4 w = *(const float4*)&W[(size_t)(g0 + bg) * K + k0 + bk];
    Bs[bk + 0][bg] = w.x; Bs[bk + 1][bg] = w.y;
    Bs[bk + 2][bg] = w.z; Bs[bk + 3][bg] = w.w;
    __syncthreads();
#pragma unroll
    for (int kt = 0; kt < 16; ++kt) {
      const float4 a  = *(const float4*)&As[kt][b0];
      const float4 g4 = *(const float4*)&Bs[kt][gq * 4];
      const float av[4] = {a.x, a.y, a.z, a.w};
      const float gv[4] = {g4.x, g4.y, g4.z, g4.w};
#pragma unroll
      for (int gi = 0; gi < 4; ++gi)
#pragma unroll
        for (int bj = 0; bj < 4; ++bj)
          acc[gi][bj] = fmaf(gv[gi], av[bj], acc[gi][bj]);
    }
    __syncthreads();
  }
#pragma unroll
  for (int gi = 0; gi < 4; ++gi) {
    int g = g0 + gq * 4 + gi;
    float bv = bias[g];
    float4 o = make_float4(acc[gi][0] + bv, acc[gi][1] + bv,
                           acc[gi][2] + bv, acc[gi][3] + bv);
    *(float4*)&xp[((size_t)ty * NG + g) * BATCH + b0] = o;
  }
}

// ---------------------------------------------------------------------------
// One GRU time step.
// xpt: xp for THIS t, [NG][BATCH]; whh: [NG][NH]; act: [T][NH][BATCH].
// grid: NH/4 = 256 blocks, 256 threads (64 b x 4 units).
__global__ __launch_bounds__(256) void k_gru_step(
    const float* __restrict__ xpt, const float* __restrict__ whh,
    const float* __restrict__ bhh, float* __restrict__ act, int t) {
  int tid = threadIdx.x;
  int b = tid & 63;
  int j = blockIdx.x * 4 + (tid >> 6);

  const float* wr = whh + (size_t)j * NH;
  const float* wz = whh + (size_t)(j + NH) * NH;
  const float* wn = whh + (size_t)(j + 2 * NH) * NH;

  float sr = 0.f, sz = 0.f, sn = 0.f;
  float h_old = 0.f;
  if (t > 0) {
    const float* hp = act + (size_t)(t - 1) * NH * BATCH + b;
    h_old = hp[(size_t)j * BATCH];
#pragma unroll 4
    for (int k = 0; k < NH; k += 4) {
      const float4 w4r = *(const float4*)&wr[k];
      const float4 w4z = *(const float4*)&wz[k];
      const float4 w4n = *(const float4*)&wn[k];
      const float h0 = hp[0];
      const float h1 = hp[BATCH];
      const float h2 = hp[2 * BATCH];
      const float h3 = hp[3 * BATCH];
      hp += 4 * BATCH;
      sr = fmaf(w4r.x, h0, sr); sz = fmaf(w4z.x, h0, sz); sn = fmaf(w4n.x, h0, sn);
      sr = fmaf(w4r.y, h1, sr); sz = fmaf(w4z.y, h1, sz); sn = fmaf(w4n.y, h1, sn);
      sr = fmaf(w4r.z, h2, sr); sz = fmaf(w4z.z, h2, sz); sn = fmaf(w4n.z, h2, sn);
      sr = fmaf(w4r.w, h3, sr); sz = fmaf(w4z.w, h3, sz); sn = fmaf(w4n.w, h3, sn);
    }
  }
  float xr = xpt[(size_t)j * BATCH + b];
  float xz = xpt[(size_t)(j + NH) * BATCH + b];
  float xn = xpt[(size_t)(j + 2 * NH) * BATCH + b];

  float r = 1.f / (1.f + expf(-(xr + sr + bhh[j])));
  float z = 1.f / (1.f + expf(-(xz + sz + bhh[j + NH])));
  float n = tanhf(xn + r * (sn + bhh[j + 2 * NH]));
  float hnew = (1.f - z) * n + z * h_old;
  act[((size_t)t * NH + j) * BATCH + b] = hnew;
}

// ---------------------------------------------------------------------------
// Final projection + L2 normalize.
// act: [T][NH][BATCH] (uses t = T-1). wp: [FCD][NH]. out: [BATCH][FCD].
// grid: BATCH blocks, FCD threads.
__global__ __launch_bounds__(256) void k_proj(
    const float* __restrict__ act, const float* __restrict__ wp,
    const float* __restrict__ bp, float* __restrict__ out) {
  int b = blockIdx.x;
  int f = threadIdx.x;
  __shared__ float hs[NH];
  __shared__ float red[FCD];

  const float* hlast = act + (size_t)(T_FRAMES - 1) * NH * BATCH + b;
  for (int k = f; k < NH; k += FCD) hs[k] = hlast[(size_t)k * BATCH];
  __syncthreads();

  float acc = bp[f];
  const float* wrow = wp + (size_t)f * NH;
#pragma unroll 4
  for (int k = 0; k < NH; k += 4) {
    const float4 w4 = *(const float4*)&wrow[k];
    acc = fmaf(w4.x, hs[k], acc);
    acc = fmaf(w4.y, hs[k + 1], acc);
    acc = fmaf(w4.z, hs[k + 2], acc);
    acc = fmaf(w4.w, hs[k + 3], acc);
  }
  red[f] = acc * acc;
  __syncthreads();
  for (int s = FCD / 2; s > 0; s >>= 1) {
    if (f < s) red[f] += red[f + s];
    __syncthreads();
  }
  float nrm = sqrtf(red[0]);
  out[(size_t)b * FCD + f] = acc / fmaxf(nrm, 1e-12f);
}

// ---------------------------------------------------------------------------
extern "C" void kernel_launch(void* const* d_in, const int* in_sizes, int n_in,
                              void* d_out, int out_size, void* d_ws, size_t ws_size,
                              hipStream_t stream) {
  const float* x        = (const float*)d_in[0];
  const float* wih0     = (const float*)d_in[1];
  const float* whh0     = (const float*)d_in[2];
  const float* bih0     = (const float*)d_in[3];
  const float* bhh0     = (const float*)d_in[4];
  const float* wih_rest = (const float*)d_in[5];
  const float* whh_rest = (const float*)d_in[6];
  const float* bih_rest = (const float*)d_in[7];
  const float* bhh_rest = (const float*)d_in[8];
  const float* wp       = (const float*)d_in[9];
  const float* bp       = (const float*)d_in[10];
  float* out = (float*)d_out;

  // ---- workspace layout (fp32 elements), sized to fit ws_size ----
  const size_t act_elems = (size_t)T_FRAMES * NH * BATCH;    // 16,777,216 (64 MiB)
  const size_t xT_elems  = (size_t)T_FRAMES * NMELS * BATCH; //  1,310,720 (5 MiB)
  const size_t fixed     = act_elems + xT_elems;

  float* act = (float*)d_ws;          // single buffer, aliased across layers
  float* xT  = act + act_elems;
  float* xp  = xT + xT_elems;         // chunk buffer: Tc * NG * BATCH

  // pick largest power-of-two chunk Tc (frames of xp) that fits
  size_t ws_elems = ws_size / sizeof(float);
  int Tc = 0;
  for (int c = T_FRAMES; c >= 1; c >>= 1) {
    if (fixed + (size_t)c * NG * BATCH <= ws_elems) { Tc = c; break; }
  }
  if (Tc == 0) return;  // cannot fit minimal plan; fail cleanly, don't fault

  const size_t xp_stride = (size_t)NG * BATCH;  // per-frame xp elements

  k_transpose_x<<<T_FRAMES, 256, 0, stream>>>(x, xT);

  for (int layer = 0; layer < 3; ++layer) {
    const float* A;   int K;
    const float* wih; const float* whh; const float* bih; const float* bhh;
    if (layer == 0) {
      A = xT; K = NMELS;
      wih = wih0; whh = whh0; bih = bih0; bhh = bhh0;
    } else {
      A = act; K = NH;
      wih = wih_rest + (size_t)(layer - 1) * NG * NH;
      whh = whh_rest + (size_t)(layer - 1) * NG * NH;
      bih = bih_rest + (size_t)(layer - 1) * NG;
      bhh = bhh_rest + (size_t)(layer - 1) * NG;
    }
    for (int c0 = 0; c0 < T_FRAMES; c0 += Tc) {
      dim3 gg(NG / 64, Tc);
      k_gemm_xp<<<gg, 256, 0, stream>>>(A, wih, bih, xp, K, c0);
      for (int t = c0; t < c0 + Tc; ++t)
        k_gru_step<<<NH / 4, 256, 0, stream>>>(
            xp + (size_t)(t - c0) * xp_stride, whh, bhh, act, t);
    }
  }

  k_proj<<<BATCH, FCD, 0, stream>>>(act, wp, bp, out);
}

// Round 3
// 14581.204 us; speedup vs baseline: 2.3473x; 2.3473x over previous
//
#include <hip/hip_runtime.h>
#include <math.h>

#define T_FRAMES 256
#define BATCH    64
#define NH       1024
#define NG       3072   // 3*NH
#define NMELS    80
#define FCD      256

#define JB 4    // h-units per block in step kernel
#define KW 128  // k-slice per wave (8 waves * 128 = 1024)

// ---------------------------------------------------------------------------
// Transpose x: [b][t][i] -> xT [t][i][b]
__global__ __launch_bounds__(256) void k_transpose_x(
    const float* __restrict__ x, float* __restrict__ xT) {
  int t = blockIdx.x;
  __shared__ float tile[BATCH][NMELS + 1];
  for (int idx = threadIdx.x; idx < BATCH * NMELS; idx += 256) {
    int b = idx / NMELS, i = idx % NMELS;
    tile[b][i] = x[((size_t)b * T_FRAMES + t) * NMELS + i];
  }
  __syncthreads();
  for (int idx = threadIdx.x; idx < BATCH * NMELS; idx += 256) {
    int i = idx / BATCH, b = idx % BATCH;
    xT[((size_t)t * NMELS + i) * BATCH + b] = tile[b][i];
  }
}

// ---------------------------------------------------------------------------
// xp[ty][g][b] = sum_k A[t0+ty][k][b] * W[g][k] + bias[g]
// grid: (NG/64, Tc), block 256.
__global__ __launch_bounds__(256) void k_gemm_xp(
    const float* __restrict__ A, const float* __restrict__ W,
    const float* __restrict__ bias, float* __restrict__ xp, int K, int t0) {
  int ty = blockIdx.y;
  int t  = t0 + ty;
  int g0 = blockIdx.x * 64;
  __shared__ float As[16][64];
  __shared__ float Bs[16][64];

  int tid = threadIdx.x;
  int b0 = (tid & 15) * 4;
  int gq = tid >> 4;
  int ar = tid >> 4;
  int ac = (tid & 15) * 4;
  int bg = tid & 63;
  int bk = (tid >> 6) * 4;

  float acc[4][4] = {{0.f}};
  const float* At = A + (size_t)t * K * BATCH;

  for (int k0 = 0; k0 < K; k0 += 16) {
    *(float4*)&As[ar][ac] = *(const float4*)&At[(size_t)(k0 + ar) * BATCH + ac];
    float4 w = *(const float4*)&W[(size_t)(g0 + bg) * K + k0 + bk];
    Bs[bk + 0][bg] = w.x; Bs[bk + 1][bg] = w.y;
    Bs[bk + 2][bg] = w.z; Bs[bk + 3][bg] = w.w;
    __syncthreads();
#pragma unroll
    for (int kt = 0; kt < 16; ++kt) {
      const float4 a  = *(const float4*)&As[kt][b0];
      const float4 g4 = *(const float4*)&Bs[kt][gq * 4];
      const float av[4] = {a.x, a.y, a.z, a.w};
      const float gv[4] = {g4.x, g4.y, g4.z, g4.w};
#pragma unroll
      for (int gi = 0; gi < 4; ++gi)
#pragma unroll
        for (int bj = 0; bj < 4; ++bj)
          acc[gi][bj] = fmaf(gv[gi], av[bj], acc[gi][bj]);
    }
    __syncthreads();
  }
#pragma unroll
  for (int gi = 0; gi < 4; ++gi) {
    int g = g0 + gq * 4 + gi;
    float bv = bias[g];
    float4 o = make_float4(acc[gi][0] + bv, acc[gi][1] + bv,
                           acc[gi][2] + bv, acc[gi][3] + bv);
    *(float4*)&xp[((size_t)ty * NG + g) * BATCH + b0] = o;
  }
}

// ---------------------------------------------------------------------------
// One GRU time step, high-occupancy split-K version.
// grid: NH/JB = 256 blocks, 512 threads = 8 waves.
// Block owns JB=4 h-units (12 gate rows). Wave w covers k in [w*KW, w*KW+KW).
// Lanes = batch. Phase 2: 256 threads reduce + gate + write.
__global__ __launch_bounds__(512) void k_gru_step2(
    const float* __restrict__ xpt, const float* __restrict__ whh,
    const float* __restrict__ bhh, float* __restrict__ act, int t) {
  const int tid  = threadIdx.x;
  const int lane = tid & 63;            // b
  const int wv   = tid >> 6;            // wave 0..7
  const int j0   = blockIdx.x * JB;

  __shared__ float part[8][JB][3][BATCH];   // 24 KB

  float sum[JB][3];
#pragma unroll
  for (int j = 0; j < JB; ++j)
#pragma unroll
    for (int g = 0; g < 3; ++g) sum[j][g] = 0.f;

  if (t > 0) {
    // wave-uniform k base (helps the compiler scalarize weight addresses)
    const int k0 = __builtin_amdgcn_readfirstlane(wv * KW);
    const float* __restrict__ hp = act + ((size_t)(t - 1) * NH) * BATCH;

#pragma unroll 2
    for (int kk = 0; kk < KW; kk += 4) {
      const int k = k0 + kk;
      const float h0 = hp[(size_t)(k + 0) * BATCH + lane];
      const float h1 = hp[(size_t)(k + 1) * BATCH + lane];
      const float h2 = hp[(size_t)(k + 2) * BATCH + lane];
      const float h3 = hp[(size_t)(k + 3) * BATCH + lane];
#pragma unroll
      for (int j = 0; j < JB; ++j) {
#pragma unroll
        for (int g = 0; g < 3; ++g) {
          const float4 w4 = *(const float4*)&whh[((size_t)(g * NH + j0 + j)) * NH + k];
          float s = sum[j][g];
          s = fmaf(w4.x, h0, s);
          s = fmaf(w4.y, h1, s);
          s = fmaf(w4.z, h2, s);
          s = fmaf(w4.w, h3, s);
          sum[j][g] = s;
        }
      }
    }
  }

#pragma unroll
  for (int j = 0; j < JB; ++j)
#pragma unroll
    for (int g = 0; g < 3; ++g) part[wv][j][g][lane] = sum[j][g];
  __syncthreads();

  if (tid < JB * BATCH) {
    const int j = tid >> 6;
    const int b = tid & 63;
    float sr = 0.f, sz = 0.f, sn = 0.f;
#pragma unroll
    for (int ww = 0; ww < 8; ++ww) {
      sr += part[ww][j][0][b];
      sz += part[ww][j][1][b];
      sn += part[ww][j][2][b];
    }
    const int jj = j0 + j;
    float h_old = 0.f;
    if (t > 0) h_old = act[((size_t)(t - 1) * NH + jj) * BATCH + b];

    const float xr = xpt[(size_t)(0 * NH + jj) * BATCH + b];
    const float xz = xpt[(size_t)(1 * NH + jj) * BATCH + b];
    const float xn = xpt[(size_t)(2 * NH + jj) * BATCH + b];

    const float r = 1.f / (1.f + expf(-(xr + sr + bhh[jj])));
    const float z = 1.f / (1.f + expf(-(xz + sz + bhh[NH + jj])));
    const float n = tanhf(xn + r * (sn + bhh[2 * NH + jj]));
    const float hnew = (1.f - z) * n + z * h_old;
    act[((size_t)t * NH + jj) * BATCH + b] = hnew;
  }
}

// ---------------------------------------------------------------------------
// Final projection + L2 normalize.
__global__ __launch_bounds__(256) void k_proj(
    const float* __restrict__ act, const float* __restrict__ wp,
    const float* __restrict__ bp, float* __restrict__ out) {
  int b = blockIdx.x;
  int f = threadIdx.x;
  __shared__ float hs[NH];
  __shared__ float red[FCD];

  const float* hlast = act + (size_t)(T_FRAMES - 1) * NH * BATCH + b;
  for (int k = f; k < NH; k += FCD) hs[k] = hlast[(size_t)k * BATCH];
  __syncthreads();

  float acc = bp[f];
  const float* wrow = wp + (size_t)f * NH;
#pragma unroll 4
  for (int k = 0; k < NH; k += 4) {
    const float4 w4 = *(const float4*)&wrow[k];
    acc = fmaf(w4.x, hs[k], acc);
    acc = fmaf(w4.y, hs[k + 1], acc);
    acc = fmaf(w4.z, hs[k + 2], acc);
    acc = fmaf(w4.w, hs[k + 3], acc);
  }
  red[f] = acc * acc;
  __syncthreads();
  for (int s = FCD / 2; s > 0; s >>= 1) {
    if (f < s) red[f] += red[f + s];
    __syncthreads();
  }
  float nrm = sqrtf(red[0]);
  out[(size_t)b * FCD + f] = acc / fmaxf(nrm, 1e-12f);
}

// ---------------------------------------------------------------------------
extern "C" void kernel_launch(void* const* d_in, const int* in_sizes, int n_in,
                              void* d_out, int out_size, void* d_ws, size_t ws_size,
                              hipStream_t stream) {
  const float* x        = (const float*)d_in[0];
  const float* wih0     = (const float*)d_in[1];
  const float* whh0     = (const float*)d_in[2];
  const float* bih0     = (const float*)d_in[3];
  const float* bhh0     = (const float*)d_in[4];
  const float* wih_rest = (const float*)d_in[5];
  const float* whh_rest = (const float*)d_in[6];
  const float* bih_rest = (const float*)d_in[7];
  const float* bhh_rest = (const float*)d_in[8];
  const float* wp       = (const float*)d_in[9];
  const float* bp       = (const float*)d_in[10];
  float* out = (float*)d_out;

  const size_t act_elems = (size_t)T_FRAMES * NH * BATCH;    // 64 MiB
  const size_t xT_elems  = (size_t)T_FRAMES * NMELS * BATCH; //  5 MiB
  const size_t fixed     = act_elems + xT_elems;

  float* act = (float*)d_ws;
  float* xT  = act + act_elems;
  float* xp  = xT + xT_elems;

  size_t ws_elems = ws_size / sizeof(float);
  int Tc = 0;
  for (int c = T_FRAMES; c >= 1; c >>= 1) {
    if (fixed + (size_t)c * NG * BATCH <= ws_elems) { Tc = c; break; }
  }
  if (Tc == 0) return;

  const size_t xp_stride = (size_t)NG * BATCH;

  k_transpose_x<<<T_FRAMES, 256, 0, stream>>>(x, xT);

  for (int layer = 0; layer < 3; ++layer) {
    const float* A;   int K;
    const float* wih; const float* whh; const float* bih; const float* bhh;
    if (layer == 0) {
      A = xT; K = NMELS;
      wih = wih0; whh = whh0; bih = bih0; bhh = bhh0;
    } else {
      A = act; K = NH;
      wih = wih_rest + (size_t)(layer - 1) * NG * NH;
      whh = whh_rest + (size_t)(layer - 1) * NG * NH;
      bih = bih_rest + (size_t)(layer - 1) * NG;
      bhh = bhh_rest + (size_t)(layer - 1) * NG;
    }
    for (int c0 = 0; c0 < T_FRAMES; c0 += Tc) {
      dim3 gg(NG / 64, Tc);
      k_gemm_xp<<<gg, 256, 0, stream>>>(A, wih, bih, xp, K, c0);
      for (int t = c0; t < c0 + Tc; ++t)
        k_gru_step2<<<NH / JB, 512, 0, stream>>>(
            xp + (size_t)(t - c0) * xp_stride, whh, bhh, act, t);
    }
  }

  k_proj<<<BATCH, FCD, 0, stream>>>(act, wp, bp, out);
}